// Round 3
// baseline (3225.368 us; speedup 1.0000x reference)
//
#include <hip/hip_runtime.h>
#include <math.h>

#define BB 32
#define NN 5000
#define EE 500
#define AT 50
#define TTT 4
#define ITT 24
#define FT 384
#define FI 383
#define KH 100
#define BN (BB*NN)

__device__ __forceinline__ float leaky(float x){ return x > 0.f ? x : 0.1f*x; }
__device__ __forceinline__ float sigm(float x){ return 1.f/(1.f+__expf(-x)); }

// workspace offsets (floats).
enum : size_t {
  O_WTT = 0,         // 19968  W_text^T padded [f][52]
  O_WIT = 19968,     // 19968  W_img^T padded [f][52] (row 383 zero)
  O_WIP = 39936,     // 10400  W_iproj*g PERMUTED [(t*13+q)*50+d][4]
  O_WTP = 50336,     // 62400  W_tproj*g PERMUTED [(i*13+q)*50+d][4]
  O_W1T = 112736,    // 50000  (unused)
  O_W3T = 162736,    // 50000  W3^T [k][500]
  O_SIP = 212736,    // 208    sum_d Wg_iproj [t][52]
  O_STP = 212944,    // 1248   sum_d Wg_tproj [i][52]
  O_CBI = 214192,    // 52     2*sum(lnb*W_iproj)+b_iproj, pad 0
  O_CBT = 214244,    // 52
  O_RGI = 214296,    // 3072   sigmoid(rel@Wrel1^T+b) [b][96]
  O_RGT = 217368,    // 3072
  O_RB  = 220440,    // 3200   rel@W1[:,E:]^T [b][100]
  O_A   = 223640,    // 500000 A^T [k][n]  (k-major)
  O_PT  = 723640,    // 16000  pos_t [b][500]
  O_PTN = 739640,    // 32
  O_PIM = 739672,    // 1664   pos_img [b][52]
  O_PIMN= 741336,    // 32
  O_PTX = 741368,    // 1664
  O_PTXN= 743032,    // 32
  O_MR  = 743064,    // 96
  O_SR  = 743160,    // 96
  O_EMB = 743256,    // 7280000 emb [n][28][52]: rows 0..3 text, 4..27 img
};

// ---------------- weight preprocessing ----------------
__global__ void k_prep(const float* Wt, const float* Wi, const float* Wip, const float* Wtp,
                       const float* W1, const float* W3, const float* g, const float* lb,
                       const float* bip, const float* btp, float* ws){
  (void)W1;
  int id = blockIdx.x*256 + threadIdx.x;
  if (id < 19968){ int f=id/52, d=id%52; ws[O_WTT+id] = (d<50)? Wt[d*FT+f] : 0.f; return; }
  id -= 19968;
  if (id < 19968){ int f=id/52, d=id%52; ws[O_WIT+id] = (f<383 && d<50)? Wi[d*FI+f] : 0.f; return; }
  id -= 19968;
  if (id < 10400){ // permuted: [(t*13+q)*50+d][c], value = Wip[(q*4+c)*200+t*50+d]*g[o]
    int m=id>>2, c=id&3; int d=m%50, r=m/50; int q=r%13, t=r/13; int o=q*4+c;
    ws[O_WIP+id] = (o<50)? Wip[o*200+t*50+d]*g[o] : 0.f; return; }
  id -= 10400;
  if (id < 62400){ // permuted: [(i*13+q)*50+d][c]
    int m=id>>2, c=id&3; int d=m%50, r=m/50; int q=r%13, i=r/13; int o=q*4+c;
    ws[O_WTP+id] = (o<50)? Wtp[o*1200+i*50+d]*g[o] : 0.f; return; }
  id -= 62400;
  if (id < 50000){ int k=id/500, e=id%500; ws[O_W3T+id] = W3[e*100+k]; return; }
  id -= 50000;
  if (id < 208){ int t=id/52, o=id%52; float s=0;
                 if (o<50) for(int d=0;d<50;d++) s += Wip[o*200+t*50+d]*g[d];
                 ws[O_SIP+id]=s; return; }
  id -= 208;
  if (id < 1248){ int i=id/52, o=id%52; float s=0;
                  if (o<50) for(int d=0;d<50;d++) s += Wtp[o*1200+i*50+d]*g[d];
                  ws[O_STP+id]=s; return; }
  id -= 1248;
  if (id < 52){ int o=id; float s=0;
                if (o<50){ for(int j=0;j<200;j++) s += lb[j%50]*Wip[o*200+j]; s=2.f*s+bip[o]; }
                ws[O_CBI+o]=s; return; }
  id -= 52;
  if (id < 52){ int o=id; float s=0;
                if (o<50){ for(int j=0;j<1200;j++) s += lb[j%50]*Wtp[o*1200+j]; s=2.f*s+btp[o]; }
                ws[O_CBT+o]=s; return; }
}

// ---------------- per-batch relation gates ----------------
__global__ void k_rel(const int* ps, const float* rele, const float* Wr1, const float* br1,
                      const float* Wr2, const float* br2, const float* W1, float* ws){
  __shared__ float relL[EE];
  int b = blockIdx.x;
  int r = ps[b*3+1];
  for (int e=threadIdx.x; e<EE; e+=256) relL[e] = rele[(size_t)r*EE+e];
  __syncthreads();
  for (int j=threadIdx.x; j<292; j+=256){
    if (j<96){
      float a=br1[j]; const float* w=&Wr1[j*EE];
      for(int e=0;e<EE;e++) a+=relL[e]*w[e];
      ws[O_RGI+b*96+j]=sigm(a);
    } else if (j<192){
      int jj=j-96; float a=br2[jj]; const float* w=&Wr2[jj*EE];
      for(int e=0;e<EE;e++) a+=relL[e]*w[e];
      ws[O_RGT+b*96+jj]=sigm(a);
    } else {
      int k=j-192; float a=0; const float* w=&W1[k*1000+500];
      for(int e=0;e<EE;e++) a+=relL[e]*w[e];
      ws[O_RB+b*100+k]=a;
    }
  }
}

// ---------------- A^T[k,n] = (ent @ W1[:, :E]^T)^T ----------------
__global__ void k_A(const float* ent, const float* W1, float* ws){
  __shared__ __align__(16) float entL[8*EE];
  int n0 = blockIdx.x*8;
  for (int idx=threadIdx.x; idx<1000; idx+=256)
    *(float4*)&entL[idx*4] = *(const float4*)&ent[(size_t)n0*EE + idx*4];
  __syncthreads();
  for (int idx=threadIdx.x; idx<800; idx+=256){
    int k=idx>>3, rr=idx&7;
    const float4* el=(const float4*)&entL[rr*EE];
    const float4* wr=(const float4*)&W1[(size_t)k*1000];
    float s=0;
    for (int e4=0;e4<125;e4++){
      float4 a=el[e4], w=wr[e4];
      s += a.x*w.x + a.y*w.y + a.z*w.z + a.w*w.w;
    }
    ws[O_A + (size_t)k*NN + (n0+rr)] = s;
  }
}

// ---------------- pos_t vectors ----------------
__global__ void k_pos(const int* ps, const float* ent, const float* b1, const float* b3, float* ws){
  __shared__ float hL[KH];
  __shared__ float red[4];
  int b=blockIdx.x; int n=ps[b*3+2]; int tid=threadIdx.x;
  if (tid<KH) hL[tid] = leaky(ws[O_A+(size_t)tid*NN+n] + ws[O_RB+b*100+tid] + b1[tid]);
  __syncthreads();
  const float* w3t=&ws[O_W3T];
  float sq=0;
  for (int e=tid; e<EE; e+=256){
    float a=b3[e];
    for (int k=0;k<KH;k++) a += hL[k]*w3t[k*500+e];
    float gg=sigm(a); float ta=ent[(size_t)n*EE+e]*gg;
    ws[O_PT+b*500+e]=ta; sq+=ta*ta;
  }
  for (int off=1; off<64; off<<=1) sq += __shfl_xor(sq, off);
  if ((tid&63)==0) red[tid>>6]=sq;
  __syncthreads();
  if (tid==0) ws[O_PTN+b] = sqrtf(red[0]+red[1]+red[2]+red[3]);
}

// ---------------- embedding GEMM, 3-stage: bias-init, F-split accumulate, leaky ----------------
__global__ void k_emb_bias(const float* bias, float* emb, int R, int rowsPerN, int rowOff){
  int row = blockIdx.x*256 + threadIdx.x;
  if (row >= R) return;
  int n = row / rowsPerN, rr = row % rowsPerN;
  float* dst = emb + (size_t)n*1456 + (size_t)(rowOff+rr)*52;
  #pragma unroll
  for (int c=0;c<13;c++){
    float4 v;
    v.x = bias[c*4+0];
    v.y = bias[c*4+1];
    v.z = (c<12)? bias[c*4+2] : 0.f;
    v.w = (c<12)? bias[c*4+3] : 0.f;
    *(float4*)&dst[c*4] = v;
  }
}

// grid = rowBlocks*4; chunk ch covers f in [ch*96, min(F,(ch+1)*96)).
// W rows read from global with wave-uniform address (L2-resident broadcast).
__global__ __launch_bounds__(256) void k_emb_acc(const float* X, const float* Wp,
                                                 float* emb, int R, int F, int rowsPerN,
                                                 int rowOff, int xstride){
  int rb = blockIdx.x >> 2, ch = blockIdx.x & 3;
  int row = rb*256 + threadIdx.x;
  if (row >= R) return;
  int f0 = ch*96;
  int nf = min(96, F - f0);
  const float* xr = X + (size_t)row*xstride + f0;
  const float4* wp = (const float4*)&Wp[(size_t)f0*52];
  float4 acc[13];
  #pragma unroll
  for (int c=0;c<13;c++) acc[c]=make_float4(0,0,0,0);
  for (int f=0; f<nf; ++f){
    float x = xr[f];
    const float4* wr = wp + (size_t)f*13;
    #pragma unroll
    for (int c=0;c<13;++c){
      float4 w=wr[c];
      acc[c].x+=x*w.x; acc[c].y+=x*w.y; acc[c].z+=x*w.z; acc[c].w+=x*w.w;
    }
  }
  int n = row / rowsPerN, rr = row % rowsPerN;
  float* dst = emb + (size_t)n*1456 + (size_t)(rowOff+rr)*52;
  #pragma unroll
  for (int c=0;c<12;c++){
    atomicAdd(&dst[c*4+0], acc[c].x);
    atomicAdd(&dst[c*4+1], acc[c].y);
    atomicAdd(&dst[c*4+2], acc[c].z);
    atomicAdd(&dst[c*4+3], acc[c].w);
  }
  atomicAdd(&dst[48], acc[12].x);
  atomicAdd(&dst[49], acc[12].y);
}

__global__ void k_emb_fin(float* emb, int total4){
  int idx = blockIdx.x*256 + threadIdx.x;
  int stride = gridDim.x*256;
  for (int i=idx; i<total4; i+=stride){
    float4 v = *(float4*)&emb[(size_t)i*4];
    v.x=leaky(v.x); v.y=leaky(v.y); v.z=leaky(v.z); v.w=leaky(v.w);
    *(float4*)&emb[(size_t)i*4]=v;
  }
}

// ---------------- fused per-n kernel (mode 0: all n; mode 1: pos rows per b) ----------------
__global__ __launch_bounds__(256) void k_main(const int* ps, float* ws, float* out, int mode){
  __shared__ __align__(16) float teie[1456];
  __shared__ __align__(16) float Pm[120*52];
  __shared__ __align__(16) float Um[120*32];
  __shared__ __align__(16) float Gi[576];
  __shared__ __align__(16) float crs[96];
  __shared__ __align__(16) float aimg[96], atxt[96];
  __shared__ __align__(16) float part1[96], part2[96];
  __shared__ __align__(16) float aU[120];
  __shared__ float Gts[16], mimg[24], mtxt[4];
  __shared__ float muA1[4], muA2[24];
  __shared__ float accD1[32], accN1[32], accD2[32], accN2[32];

  int tid = threadIdx.x;
  int bstar = blockIdx.x;
  int n = mode ? ps[bstar*3+2] : blockIdx.x;

  // P0: stage emb row block, zero accumulators
  const float* embn = &ws[O_EMB + (size_t)n*1456];
  for (int j=tid; j<364; j+=256) *(float4*)&teie[j*4] = *(const float4*)&embn[j*4];
  if (tid<32){ accD1[tid]=0.f; accN1[tid]=0.f; accD2[tid]=0.f; accN2[tid]=0.f; }
  __syncthreads();

  // P1: Gram matrices, cross, means (vectorized; pad cols 50,51 are zero)
  for (int it=tid; it<716; it+=256){
    if (it<576){
      int i=it/24, j=it%24;
      const float4* a=(const float4*)&teie[(4+i)*52];
      const float4* b=(const float4*)&teie[(4+j)*52];
      float s=0;
      #pragma unroll
      for(int d=0;d<13;d++){ float4 x=a[d], y=b[d]; s+=x.x*y.x+x.y*y.y+x.z*y.z+x.w*y.w; }
      Gi[it]=s;
    } else if (it<672){
      int c=it-576; int i=c>>2, t=c&3;
      const float4* a=(const float4*)&teie[(4+i)*52];
      const float4* b=(const float4*)&teie[t*52];
      float s=0;
      #pragma unroll
      for(int d=0;d<13;d++){ float4 x=a[d], y=b[d]; s+=x.x*y.x+x.y*y.y+x.z*y.z+x.w*y.w; }
      crs[c]=s;
    } else if (it<688){
      int c=it-672; int t=c>>2, u=c&3;
      const float4* a=(const float4*)&teie[t*52];
      const float4* b=(const float4*)&teie[u*52];
      float s=0;
      #pragma unroll
      for(int d=0;d<13;d++){ float4 x=a[d], y=b[d]; s+=x.x*y.x+x.y*y.y+x.z*y.z+x.w*y.w; }
      Gts[c]=s;
    } else if (it<712){
      int i=it-688;
      const float4* a=(const float4*)&teie[(4+i)*52];
      float s=0;
      #pragma unroll
      for(int d=0;d<13;d++){ float4 x=a[d]; s+=x.x+x.y+x.z+x.w; }
      mimg[i]=s*0.02f;
    } else {
      int t=it-712;
      const float4* a=(const float4*)&teie[t*52];
      float s=0;
      #pragma unroll
      for(int d=0;d<13;d++){ float4 x=a[d]; s+=x.x+x.y+x.z+x.w; }
      mtxt[t]=s*0.02f;
    }
  }
  __syncthreads();

  // P2: attention softmaxes + means
  if (tid<4){
    int t=tid;
    float mx=-1e30f; for(int i=0;i<24;i++) mx=fmaxf(mx,crs[i*4+t]);
    float ex[24]; float s=0;
    for(int i=0;i<24;i++){ ex[i]=__expf(crs[i*4+t]-mx); s+=ex[i]; }
    float inv=1.f/s; float mu=0;
    for(int i=0;i<24;i++){ float a=ex[i]*inv; aimg[i*4+t]=a; mu+=a*mimg[i]; }
    muA1[t]=mu;
  } else if (tid>=64 && tid<88){
    int i=tid-64;
    float mx=-1e30f; for(int t=0;t<4;t++) mx=fmaxf(mx,crs[i*4+t]);
    float ex[4]; float s=0;
    for(int t=0;t<4;t++){ ex[t]=__expf(crs[i*4+t]-mx); s+=ex[t]; }
    float inv=1.f/s; float mu=0;
    for(int t=0;t<4;t++){ float a=ex[t]*inv; atxt[i*4+t]=a; mu+=a*mtxt[t]; }
    muA2[i]=mu;
  }
  __syncthreads();

  // P3: img Pm build (retiled: lane=(t,q,ig), 6 i-rows; w streamed from L2)
  if (tid<208){
    int ig=tid&3, r=tid>>2, q=r%13, t=r/13;
    const float* wb = &ws[O_WIP + (size_t)(t*13+q)*200];
    const float* eb = &teie[(4+ig*6)*52];
    float4 acc[6];
    #pragma unroll
    for (int l=0;l<6;l++) acc[l]=make_float4(0,0,0,0);
    for (int dc=0; dc<12; ++dc){
      float e[6][4];
      #pragma unroll
      for (int l=0;l<6;l++){
        float4 v=*(const float4*)&eb[l*52+dc*4];
        e[l][0]=v.x; e[l][1]=v.y; e[l][2]=v.z; e[l][3]=v.w;
      }
      #pragma unroll
      for (int dd=0; dd<4; ++dd){
        float4 w=*(const float4*)&wb[(dc*4+dd)*4];
        #pragma unroll
        for (int l=0;l<6;l++){
          acc[l].x+=e[l][dd]*w.x; acc[l].y+=e[l][dd]*w.y;
          acc[l].z+=e[l][dd]*w.z; acc[l].w+=e[l][dd]*w.w;
        }
      }
    }
    #pragma unroll
    for (int d=48; d<50; ++d){
      float4 w=*(const float4*)&wb[d*4];
      #pragma unroll
      for (int l=0;l<6;l++){
        float ee=eb[l*52+d];
        acc[l].x+=ee*w.x; acc[l].y+=ee*w.y; acc[l].z+=ee*w.z; acc[l].w+=ee*w.w;
      }
    }
    #pragma unroll
    for (int l=0;l<6;l++) *(float4*)&Pm[(t*24+ig*6+l)*52 + q*4]=acc[l];
  } else {
    // lanes 208..255: part1 (96), part2 (96), Sip copy (52 float4)
    for (int c=tid-208; c<244; c+=48){
      if (c<96){
        int i=c>>2, t=c&3;
        float s=0; for(int j=0;j<24;j++) s+=Gi[i*24+j]*aimg[j*4+t];
        part1[c]=aimg[c]*s;
      } else if (c<192){
        int cc=c-96; int t=cc&3;
        float s=0; for(int u=0;u<4;u++) s+=Gts[t*4+u]*atxt[(cc&~3)+u];
        part2[cc]=atxt[cc]*s;
      } else {
        int j=c-192;
        *(float4*)&Pm[96*52+j*4] = *(const float4*)&ws[O_SIP+j*4];
      }
    }
  }
  __syncthreads();

  // P4: img LN stats -> Um ; att aU
  if (tid<128){
    int b=tid&31, t=tid>>5;
    float w1r[24];
    #pragma unroll
    for(int i=0;i<24;i++) w1r[i]=ws[O_RGI+b*96+i*4+t]*crs[i*4+t];
    float mu=0;
    #pragma unroll
    for(int i=0;i<24;i++) mu+=w1r[i]*mimg[i];
    float q=0;
    #pragma unroll
    for(int i=0;i<24;i++){
      const float4* gr=(const float4*)&Gi[i*24];
      float s=0;
      #pragma unroll
      for(int j4=0;j4<6;j4++){
        float4 g=gr[j4];
        s+=g.x*w1r[j4*4]+g.y*w1r[j4*4+1]+g.z*w1r[j4*4+2]+g.w*w1r[j4*4+3];
      }
      q+=w1r[i]*s;
    }
    float inv=rsqrtf(q*0.02f-mu*mu+1e-5f);
    #pragma unroll
    for(int i=0;i<24;i++) Um[(t*24+i)*32+b]=inv*w1r[i];
    Um[(96+t)*32+b]=-inv*mu;
  } else if (tid<228){
    int z=tid-128;
    int t=(z<96)? (z/24) : (z-96);
    float q=0; for(int i=0;i<24;i++) q+=part1[i*4+t];
    float inv=rsqrtf(q*0.02f-muA1[t]*muA1[t]+1e-5f);
    aU[z]=(z<96)? inv*aimg[(z%24)*4+t] : -inv*muA1[t];
  }
  __syncthreads();

  // P5: img GEMM (4b x 4o per lane) + aU fold + CBI + fused cos-sim partials
  if (tid<104){
    int bg=tid/13, q=tid-bg*13;
    float4 a0=make_float4(0,0,0,0), a1=make_float4(0,0,0,0);
    float4 a2=make_float4(0,0,0,0), a3=make_float4(0,0,0,0);
    for (int z=0; z<100; ++z){
      float az=aU[z];
      float4 u=*(const float4*)&Um[z*32+bg*4];
      float4 p=*(const float4*)&Pm[z*52+q*4];
      float u0=u.x+az, u1=u.y+az, u2=u.z+az, u3=u.w+az;
      a0.x+=u0*p.x; a0.y+=u0*p.y; a0.z+=u0*p.z; a0.w+=u0*p.w;
      a1.x+=u1*p.x; a1.y+=u1*p.y; a1.z+=u1*p.z; a1.w+=u1*p.w;
      a2.x+=u2*p.x; a2.y+=u2*p.y; a2.z+=u2*p.z; a2.w+=u2*p.w;
      a3.x+=u3*p.x; a3.y+=u3*p.y; a3.z+=u3*p.z; a3.w+=u3*p.w;
    }
    float4 cb=*(const float4*)&ws[O_CBI+q*4];
    a0.x+=cb.x; a0.y+=cb.y; a0.z+=cb.z; a0.w+=cb.w;
    a1.x+=cb.x; a1.y+=cb.y; a1.z+=cb.z; a1.w+=cb.w;
    a2.x+=cb.x; a2.y+=cb.y; a2.z+=cb.z; a2.w+=cb.w;
    a3.x+=cb.x; a3.y+=cb.y; a3.z+=cb.z; a3.w+=cb.w;
    float n0=a0.x*a0.x+a0.y*a0.y+a0.z*a0.z+a0.w*a0.w;
    float n1=a1.x*a1.x+a1.y*a1.y+a1.z*a1.z+a1.w*a1.w;
    float n2=a2.x*a2.x+a2.y*a2.y+a2.z*a2.z+a2.w*a2.w;
    float n3=a3.x*a3.x+a3.y*a3.y+a3.z*a3.z+a3.w*a3.w;
    int b0=bg*4;
    if (!mode){
      const float* PV=&ws[O_PIM];
      float4 p0=*(const float4*)&PV[(b0+0)*52+q*4];
      float4 p1=*(const float4*)&PV[(b0+1)*52+q*4];
      float4 p2=*(const float4*)&PV[(b0+2)*52+q*4];
      float4 p3=*(const float4*)&PV[(b0+3)*52+q*4];
      atomicAdd(&accD1[b0+0], a0.x*p0.x+a0.y*p0.y+a0.z*p0.z+a0.w*p0.w);
      atomicAdd(&accD1[b0+1], a1.x*p1.x+a1.y*p1.y+a1.z*p1.z+a1.w*p1.w);
      atomicAdd(&accD1[b0+2], a2.x*p2.x+a2.y*p2.y+a2.z*p2.z+a2.w*p2.w);
      atomicAdd(&accD1[b0+3], a3.x*p3.x+a3.y*p3.y+a3.z*p3.z+a3.w*p3.w);
      atomicAdd(&accN1[b0+0],n0); atomicAdd(&accN1[b0+1],n1);
      atomicAdd(&accN1[b0+2],n2); atomicAdd(&accN1[b0+3],n3);
    } else {
      atomicAdd(&accN1[b0+0],n0); atomicAdd(&accN1[b0+1],n1);
      atomicAdd(&accN1[b0+2],n2); atomicAdd(&accN1[b0+3],n3);
      if ((bstar>>2)==bg){
        int bl=bstar&3;
        float4 sel = (bl==0)? a0 : (bl==1)? a1 : (bl==2)? a2 : a3;
        *(float4*)&ws[O_PIM+(size_t)bstar*52+q*4]=sel;
      }
    }
  }
  __syncthreads();

  // P6: write img sims / norms; build text Pm (retiled) + Stp copy
  if (!mode){
    if (tid<32)
      out[(size_t)BN + (size_t)tid*NN + n] = accD1[tid]/(sqrtf(accN1[tid])*ws[O_PIMN+tid]+1e-10f);
  } else {
    if (tid==0) ws[O_PIMN+bstar]=sqrtf(accN1[bstar]);
  }
  if (tid<156){
    int q=tid%13, i2=tid/13;   // i2 0..11 -> i = 2*i2, 2*i2+1
    const float* wbA = &ws[O_WTP + (size_t)((i2*2+0)*13+q)*200];
    const float* wbB = &ws[O_WTP + (size_t)((i2*2+1)*13+q)*200];
    float4 accA[4], accB[4];
    #pragma unroll
    for (int t=0;t<4;t++){ accA[t]=make_float4(0,0,0,0); accB[t]=make_float4(0,0,0,0); }
    for (int dc=0; dc<12; ++dc){
      float e[4][4];
      #pragma unroll
      for (int t=0;t<4;t++){
        float4 v=*(const float4*)&teie[t*52+dc*4];
        e[t][0]=v.x; e[t][1]=v.y; e[t][2]=v.z; e[t][3]=v.w;
      }
      #pragma unroll
      for (int dd=0; dd<4; ++dd){
        float4 wA=*(const float4*)&wbA[(dc*4+dd)*4];
        float4 wB=*(const float4*)&wbB[(dc*4+dd)*4];
        #pragma unroll
        for (int t=0;t<4;t++){
          accA[t].x+=e[t][dd]*wA.x; accA[t].y+=e[t][dd]*wA.y;
          accA[t].z+=e[t][dd]*wA.z; accA[t].w+=e[t][dd]*wA.w;
          accB[t].x+=e[t][dd]*wB.x; accB[t].y+=e[t][dd]*wB.y;
          accB[t].z+=e[t][dd]*wB.z; accB[t].w+=e[t][dd]*wB.w;
        }
      }
    }
    #pragma unroll
    for (int d=48; d<50; ++d){
      float4 wA=*(const float4*)&wbA[d*4];
      float4 wB=*(const float4*)&wbB[d*4];
      #pragma unroll
      for (int t=0;t<4;t++){
        float ee=teie[t*52+d];
        accA[t].x+=ee*wA.x; accA[t].y+=ee*wA.y; accA[t].z+=ee*wA.z; accA[t].w+=ee*wA.w;
        accB[t].x+=ee*wB.x; accB[t].y+=ee*wB.y; accB[t].z+=ee*wB.z; accB[t].w+=ee*wB.w;
      }
    }
    #pragma unroll
    for (int t=0;t<4;t++){
      *(float4*)&Pm[(t*24+i2*2+0)*52 + q*4]=accA[t];
      *(float4*)&Pm[(t*24+i2*2+1)*52 + q*4]=accB[t];
    }
  } else {
    for (int j=tid-156; j<312; j+=100)
      *(float4*)&Pm[96*52+j*4] = *(const float4*)&ws[O_STP+j*4];
  }
  __syncthreads();

  // P7: text LN stats -> Um ; att aU2
  for (int it=tid; it<888; it+=256){
    if (it<768){
      int b=it&31, i=it>>5;
      float w2r[4];
      #pragma unroll
      for(int t=0;t<4;t++) w2r[t]=ws[O_RGT+b*96+i*4+t]*crs[i*4+t];
      float mu=0;
      #pragma unroll
      for(int t=0;t<4;t++) mu+=w2r[t]*mtxt[t];
      float q=0;
      #pragma unroll
      for(int t=0;t<4;t++){
        float s=0;
        #pragma unroll
        for(int u=0;u<4;u++) s+=Gts[t*4+u]*w2r[u];
        q+=w2r[t]*s;
      }
      float inv=rsqrtf(q*0.02f-mu*mu+1e-5f);
      #pragma unroll
      for(int t=0;t<4;t++) Um[(t*24+i)*32+b]=inv*w2r[t];
      Um[(96+i)*32+b]=-inv*mu;
    } else {
      int z=it-768;
      int i=(z<96)? (z%24) : (z-96);
      float q=0; for(int t=0;t<4;t++) q+=part2[i*4+t];
      float inv=rsqrtf(q*0.02f-muA2[i]*muA2[i]+1e-5f);
      aU[z]=(z<96)? inv*atxt[(z%24)*4+(z/24)] : -inv*muA2[i];
    }
  }
  __syncthreads();

  // P8: text GEMM (4b x 4o per lane) + aU fold + CBT + fused cos-sim partials
  if (tid<104){
    int bg=tid/13, q=tid-bg*13;
    float4 a0=make_float4(0,0,0,0), a1=make_float4(0,0,0,0);
    float4 a2=make_float4(0,0,0,0), a3=make_float4(0,0,0,0);
    for (int z=0; z<120; ++z){
      float az=aU[z];
      float4 u=*(const float4*)&Um[z*32+bg*4];
      float4 p=*(const float4*)&Pm[z*52+q*4];
      float u0=u.x+az, u1=u.y+az, u2=u.z+az, u3=u.w+az;
      a0.x+=u0*p.x; a0.y+=u0*p.y; a0.z+=u0*p.z; a0.w+=u0*p.w;
      a1.x+=u1*p.x; a1.y+=u1*p.y; a1.z+=u1*p.z; a1.w+=u1*p.w;
      a2.x+=u2*p.x; a2.y+=u2*p.y; a2.z+=u2*p.z; a2.w+=u2*p.w;
      a3.x+=u3*p.x; a3.y+=u3*p.y; a3.z+=u3*p.z; a3.w+=u3*p.w;
    }
    float4 cb=*(const float4*)&ws[O_CBT+q*4];
    a0.x+=cb.x; a0.y+=cb.y; a0.z+=cb.z; a0.w+=cb.w;
    a1.x+=cb.x; a1.y+=cb.y; a1.z+=cb.z; a1.w+=cb.w;
    a2.x+=cb.x; a2.y+=cb.y; a2.z+=cb.z; a2.w+=cb.w;
    a3.x+=cb.x; a3.y+=cb.y; a3.z+=cb.z; a3.w+=cb.w;
    float n0=a0.x*a0.x+a0.y*a0.y+a0.z*a0.z+a0.w*a0.w;
    float n1=a1.x*a1.x+a1.y*a1.y+a1.z*a1.z+a1.w*a1.w;
    float n2=a2.x*a2.x+a2.y*a2.y+a2.z*a2.z+a2.w*a2.w;
    float n3=a3.x*a3.x+a3.y*a3.y+a3.z*a3.z+a3.w*a3.w;
    int b0=bg*4;
    if (!mode){
      const float* PV=&ws[O_PTX];
      float4 p0=*(const float4*)&PV[(b0+0)*52+q*4];
      float4 p1=*(const float4*)&PV[(b0+1)*52+q*4];
      float4 p2=*(const float4*)&PV[(b0+2)*52+q*4];
      float4 p3=*(const float4*)&PV[(b0+3)*52+q*4];
      atomicAdd(&accD2[b0+0], a0.x*p0.x+a0.y*p0.y+a0.z*p0.z+a0.w*p0.w);
      atomicAdd(&accD2[b0+1], a1.x*p1.x+a1.y*p1.y+a1.z*p1.z+a1.w*p1.w);
      atomicAdd(&accD2[b0+2], a2.x*p2.x+a2.y*p2.y+a2.z*p2.z+a2.w*p2.w);
      atomicAdd(&accD2[b0+3], a3.x*p3.x+a3.y*p3.y+a3.z*p3.z+a3.w*p3.w);
      atomicAdd(&accN2[b0+0],n0); atomicAdd(&accN2[b0+1],n1);
      atomicAdd(&accN2[b0+2],n2); atomicAdd(&accN2[b0+3],n3);
    } else {
      atomicAdd(&accN2[b0+0],n0); atomicAdd(&accN2[b0+1],n1);
      atomicAdd(&accN2[b0+2],n2); atomicAdd(&accN2[b0+3],n3);
      if ((bstar>>2)==bg){
        int bl=bstar&3;
        float4 sel = (bl==0)? a0 : (bl==1)? a1 : (bl==2)? a2 : a3;
        *(float4*)&ws[O_PTX+(size_t)bstar*52+q*4]=sel;
      }
    }
  }
  __syncthreads();

  // P9: write text sims / norms
  if (!mode){
    if (tid<32)
      out[2*(size_t)BN + (size_t)tid*NN + n] = accD2[tid]/(sqrtf(accN2[tid])*ws[O_PTXN+tid]+1e-10f);
  } else {
    if (tid==0) ws[O_PTXN+bstar]=sqrtf(accN2[bstar]);
  }
}

// ---------------- gate GEMM + t-path cos-sim, blocked: (b, 64-n tile) per block ----------------
__global__ __launch_bounds__(256) void k_gate(const float* ent, const float* b1, const float* b3,
                                              float* ws, float* out){
  __shared__ __align__(16) float hL[50*68];    // [k][64n] pad->68  13.6 KB
  __shared__ __align__(16) float wc[50*128];   // [k][128e]         25.6 KB
  __shared__ __align__(16) float PTb[512];     // pos_t[b] padded    2 KB
  __shared__ __align__(16) float b3L[512];     // b3 padded          2 KB
  __shared__ float rbL[KH];                    // RB[b,:]+b1

  int tid = threadIdx.x;
  int b   = blockIdx.x & 31;
  int n0  = (blockIdx.x >> 5) * 64;

  for (int j=tid; j<512; j+=256){
    PTb[j] = (j<EE)? ws[O_PT + b*EE + j] : 0.f;
    b3L[j] = (j<EE)? b3[j] : 0.f;
  }
  if (tid < KH) rbL[tid] = ws[O_RB + b*KH + tid] + b1[tid];

  int ej = tid & 31;   // e-group lane: 4 e each
  int ni = tid >> 5;   // n-group: 8 n each

  float pn[8], ps[8];
  #pragma unroll
  for (int r=0;r<8;r++){ pn[r]=0.f; ps[r]=0.f; }

  for (int ec=0; ec<4; ++ec){
    int e0 = ec*128;
    float4 acc[8];
    #pragma unroll
    for (int r=0;r<8;r++) acc[r]=make_float4(0,0,0,0);

    for (int kh=0; kh<2; ++kh){
      __syncthreads();
      for (int idx=tid; idx<1600; idx+=256){
        int k = idx>>5, j4 = idx&31;
        int e = e0 + j4*4;
        float4 v = make_float4(0,0,0,0);
        if (e+3 < EE) v = *(const float4*)&ws[O_W3T + (size_t)(kh*50+k)*EE + e];
        *(float4*)&wc[k*128 + j4*4] = v;
      }
      for (int idx=tid; idx<3200; idx+=256){
        int k = idx>>6, nn = idx&63;
        int n = n0 + nn;
        float v = 0.f;
        if (n < NN) v = leaky(ws[O_A + (size_t)(kh*50+k)*NN + n] + rbL[kh*50+k]);
        hL[k*68 + nn] = v;
      }
      __syncthreads();

      const float4* wp = (const float4*)&wc[ej*4];   // stride 32 float4 per k
      const float4* hp = (const float4*)&hL[ni*8];   // stride 17 float4 per k
      #pragma unroll 2
      for (int k=0;k<50;k++){
        float4 w  = wp[k*32];
        float4 h0 = hp[k*17];
        float4 h1 = hp[k*17 + 1];
        acc[0].x+=h0.x*w.x; acc[0].y+=h0.x*w.y; acc[0].z+=h0.x*w.z; acc[0].w+=h0.x*w.w;
        acc[1].x+=h0.y*w.x; acc[1].y+=h0.y*w.y; acc[1].z+=h0.y*w.z; acc[1].w+=h0.y*w.w;
        acc[2].x+=h0.z*w.x; acc[2].y+=h0.z*w.y; acc[2].z+=h0.z*w.z; acc[2].w+=h0.z*w.w;
        acc[3].x+=h0.w*w.x; acc[3].y+=h0.w*w.y; acc[3].z+=h0.w*w.z; acc[3].w+=h0.w*w.w;
        acc[4].x+=h1.x*w.x; acc[4].y+=h1.x*w.y; acc[4].z+=h1.x*w.z; acc[4].w+=h1.x*w.w;
        acc[5].x+=h1.y*w.x; acc[5].y+=h1.y*w.y; acc[5].z+=h1.y*w.z; acc[5].w+=h1.y*w.w;
        acc[6].x+=h1.z*w.x; acc[6].y+=h1.z*w.y; acc[6].z+=h1.z*w.z; acc[6].w+=h1.z*w.w;
        acc[7].x+=h1.w*w.x; acc[7].y+=h1.w*w.y; acc[7].z+=h1.w*w.z; acc[7].w+=h1.w*w.w;
      }
    }

    {
      int ebase = e0 + ej*4;
      bool ev = (ebase + 3) < EE;
      float4 bb = *(const float4*)&b3L[ebase];
      float4 pt = *(const float4*)&PTb[ebase];
      #pragma unroll
      for (int r=0;r<8;r++){
        int n = n0 + ni*8 + r;
        float4 en = make_float4(0,0,0,0);
        if (ev && n < NN) en = *(const float4*)&ent[(size_t)n*EE + ebase];
        float t0 = en.x * sigm(acc[r].x + bb.x);
        float t1 = en.y * sigm(acc[r].y + bb.y);
        float t2 = en.z * sigm(acc[r].z + bb.z);
        float t3 = en.w * sigm(acc[r].w + bb.w);
        pn[r] += t0*pt.x + t1*pt.y + t2*pt.z + t3*pt.w;
        ps[r] += t0*t0 + t1*t1 + t2*t2 + t3*t3;
      }
    }
  }

  for (int off=1; off<32; off<<=1){
    #pragma unroll
    for (int r=0;r<8;r++){ pn[r]+=__shfl_xor(pn[r],off); ps[r]+=__shfl_xor(ps[r],off); }
  }
  if (ej==0){
    float ptn = ws[O_PTN+b];
    #pragma unroll
    for (int r=0;r<8;r++){
      int n = n0 + ni*8 + r;
      if (n < NN)
        out[3*(size_t)BN + (size_t)b*NN + n] = pn[r]/(sqrtf(ps[r])*ptn + 1e-10f);
    }
  }
}

// ---------------- softmax pass 1 ----------------
__global__ void k_smax1(const float* out, float* ws){
  __shared__ float red[4];
  __shared__ float Msh;
  int a=blockIdx.x>>5, b=blockIdx.x&31, tid=threadIdx.x;
  const float* arr=&out[(size_t)(1+a)*BN + (size_t)b*NN];
  float mx=-1e30f;
  for (int i=tid;i<NN;i+=256) mx=fmaxf(mx,arr[i]);
  for (int off=1;off<64;off<<=1) mx=fmaxf(mx,__shfl_xor(mx,off));
  if ((tid&63)==0) red[tid>>6]=mx;
  __syncthreads();
  if (tid==0) Msh=fmaxf(fmaxf(red[0],red[1]),fmaxf(red[2],red[3]));
  __syncthreads();
  float M2=2.f*Msh;
  float s=0;
  for (int i=tid;i<NN;i+=256) s+=__expf(2.f*arr[i]-M2);
  for (int off=1;off<64;off<<=1) s+=__shfl_xor(s,off);
  if ((tid&63)==0) red[tid>>6]=s;
  __syncthreads();
  if (tid==0){ ws[O_MR+a*32+b]=M2; ws[O_SR+a*32+b]=red[0]+red[1]+red[2]+red[3]; }
}

// ---------------- softmax pass 2 ----------------
__global__ void k_smax2(float* out, const float* ws){
  int t=blockIdx.x*256+threadIdx.x;
  if (t>=BN) return;
  int b=t/NN;
  float r=0;
  for (int a=0;a<3;a++)
    r += __expf(2.f*out[(size_t)(1+a)*BN+t]-ws[O_MR+a*32+b])/ws[O_SR+a*32+b];
  out[t]=r;
}

extern "C" void kernel_launch(void* const* d_in, const int* in_sizes, int n_in,
                              void* d_out, int out_size, void* d_ws, size_t ws_size,
                              hipStream_t stream){
  (void)in_sizes; (void)n_in; (void)out_size; (void)ws_size;
  const int*   ps  =(const int*)  d_in[0];
  const float* etg =(const float*)d_in[1];
  const float* eig =(const float*)d_in[2];
  const float* ent =(const float*)d_in[3];
  const float* rele=(const float*)d_in[4];
  const float* Wt  =(const float*)d_in[5];
  const float* btx =(const float*)d_in[6];
  const float* Wi  =(const float*)d_in[7];
  const float* bim =(const float*)d_in[8];
  const float* Wtp =(const float*)d_in[9];
  const float* btp =(const float*)d_in[10];
  const float* Wip =(const float*)d_in[11];
  const float* bip =(const float*)d_in[12];
  const float* Wr1 =(const float*)d_in[13];
  const float* br1 =(const float*)d_in[14];
  const float* Wr2 =(const float*)d_in[15];
  const float* br2 =(const float*)d_in[16];
  const float* W1  =(const float*)d_in[17];
  const float* b1  =(const float*)d_in[18];
  const float* W3  =(const float*)d_in[19];
  const float* b3  =(const float*)d_in[20];
  const float* lng =(const float*)d_in[21];
  const float* lnb =(const float*)d_in[22];
  float* ws =(float*)d_ws;
  float* out=(float*)d_out;

  k_prep <<<642,256,0,stream>>>(Wt,Wi,Wip,Wtp,W1,W3,lng,lnb,bip,btp,ws);
  k_rel  <<<32, 256,0,stream>>>(ps,rele,Wr1,br1,Wr2,br2,W1,ws);
  k_A    <<<625,256,0,stream>>>(ent,W1,ws);
  k_pos  <<<32, 256,0,stream>>>(ps,ent,b1,b3,ws);
  k_emb_bias<<<79, 256,0,stream>>>(btx,&ws[O_EMB],20000,4,0);
  k_emb_bias<<<469,256,0,stream>>>(bim,&ws[O_EMB],120000,24,4);
  k_emb_acc <<<79*4, 256,0,stream>>>(etg,&ws[O_WTT],&ws[O_EMB],20000,FT,4,0,FT);
  k_emb_acc <<<469*4,256,0,stream>>>(eig,&ws[O_WIT],&ws[O_EMB],120000,FI,24,4,FI);
  k_emb_fin <<<2048,256,0,stream>>>(&ws[O_EMB],1820000);
  k_main <<<32,  256,0,stream>>>(ps,ws,out,1);
  k_main <<<5000,256,0,stream>>>(ps,ws,out,0);
  k_gate <<<32*79,256,0,stream>>>(ent,b1,b3,ws,out);
  k_smax1<<<96, 256,0,stream>>>(out,ws);
  k_smax2<<<625,256,0,stream>>>(out,ws);
}

// Round 4
// 1456.630 us; speedup vs baseline: 2.2143x; 2.2143x over previous
//
#include <hip/hip_runtime.h>
#include <math.h>

#define BB 32
#define NN 5000
#define EE 500
#define AT 50
#define TTT 4
#define ITT 24
#define FT 384
#define FI 383
#define KH 100
#define BN (BB*NN)

__device__ __forceinline__ float leaky(float x){ return x > 0.f ? x : 0.1f*x; }
__device__ __forceinline__ float sigm(float x){ return 1.f/(1.f+__expf(-x)); }

// workspace offsets (floats).
enum : size_t {
  O_WTT = 0,         // 19968  W_text^T padded [f][52]
  O_WIT = 19968,     // 19968  W_img^T padded [f][52] (row 383 zero)
  O_WIP = 39936,     // 10400  W_iproj*g PERMUTED [(t*13+q)*50+d][4]
  O_WTP = 50336,     // 62400  W_tproj*g PERMUTED [(i*13+q)*50+d][4]
  O_W1T = 112736,    // 50000  (unused)
  O_W3T = 162736,    // 50000  W3^T [k][500]
  O_SIP = 212736,    // 208    sum_d Wg_iproj [t][52]
  O_STP = 212944,    // 1248   sum_d Wg_tproj [i][52]
  O_CBI = 214192,    // 52     2*sum(lnb*W_iproj)+b_iproj, pad 0
  O_CBT = 214244,    // 52
  O_RGI = 214296,    // 3072   sigmoid(rel@Wrel1^T+b) [b][96]
  O_RGT = 217368,    // 3072
  O_RB  = 220440,    // 3200   rel@W1[:,E:]^T [b][100]
  O_A   = 223640,    // 500000 A^T [k][n]  (k-major)
  O_PT  = 723640,    // 16000  pos_t [b][500]
  O_PTN = 739640,    // 32
  O_PIM = 739672,    // 1664   pos_img [b][52]
  O_PIMN= 741336,    // 32
  O_PTX = 741368,    // 1664
  O_PTXN= 743032,    // 32
  O_MR  = 743064,    // 96
  O_SR  = 743160,    // 96
  O_EMB = 743256,    // 7280000 emb [n][28][52]: rows 0..3 text, 4..27 img
};

// ---------------- weight preprocessing ----------------
__global__ void k_prep(const float* Wt, const float* Wi, const float* Wip, const float* Wtp,
                       const float* W1, const float* W3, const float* g, const float* lb,
                       const float* bip, const float* btp, float* ws){
  (void)W1;
  int id = blockIdx.x*256 + threadIdx.x;
  if (id < 19968){ int f=id/52, d=id%52; ws[O_WTT+id] = (d<50)? Wt[d*FT+f] : 0.f; return; }
  id -= 19968;
  if (id < 19968){ int f=id/52, d=id%52; ws[O_WIT+id] = (f<383 && d<50)? Wi[d*FI+f] : 0.f; return; }
  id -= 19968;
  if (id < 10400){ // permuted: [(t*13+q)*50+d][c], value = Wip[(q*4+c)*200+t*50+d]*g[o]
    int m=id>>2, c=id&3; int d=m%50, r=m/50; int q=r%13, t=r/13; int o=q*4+c;
    ws[O_WIP+id] = (o<50)? Wip[o*200+t*50+d]*g[o] : 0.f; return; }
  id -= 10400;
  if (id < 62400){ // permuted: [(i*13+q)*50+d][c]
    int m=id>>2, c=id&3; int d=m%50, r=m/50; int q=r%13, i=r/13; int o=q*4+c;
    ws[O_WTP+id] = (o<50)? Wtp[o*1200+i*50+d]*g[o] : 0.f; return; }
  id -= 62400;
  if (id < 50000){ int k=id/500, e=id%500; ws[O_W3T+id] = W3[e*100+k]; return; }
  id -= 50000;
  if (id < 208){ int t=id/52, o=id%52; float s=0;
                 if (o<50) for(int d=0;d<50;d++) s += Wip[o*200+t*50+d]*g[d];
                 ws[O_SIP+id]=s; return; }
  id -= 208;
  if (id < 1248){ int i=id/52, o=id%52; float s=0;
                  if (o<50) for(int d=0;d<50;d++) s += Wtp[o*1200+i*50+d]*g[d];
                  ws[O_STP+id]=s; return; }
  id -= 1248;
  if (id < 52){ int o=id; float s=0;
                if (o<50){ for(int j=0;j<200;j++) s += lb[j%50]*Wip[o*200+j]; s=2.f*s+bip[o]; }
                ws[O_CBI+o]=s; return; }
  id -= 52;
  if (id < 52){ int o=id; float s=0;
                if (o<50){ for(int j=0;j<1200;j++) s += lb[j%50]*Wtp[o*1200+j]; s=2.f*s+btp[o]; }
                ws[O_CBT+o]=s; return; }
}

// ---------------- per-batch relation gates ----------------
__global__ void k_rel(const int* ps, const float* rele, const float* Wr1, const float* br1,
                      const float* Wr2, const float* br2, const float* W1, float* ws){
  __shared__ float relL[EE];
  int b = blockIdx.x;
  int r = ps[b*3+1];
  for (int e=threadIdx.x; e<EE; e+=256) relL[e] = rele[(size_t)r*EE+e];
  __syncthreads();
  for (int j=threadIdx.x; j<292; j+=256){
    if (j<96){
      float a=br1[j]; const float* w=&Wr1[j*EE];
      for(int e=0;e<EE;e++) a+=relL[e]*w[e];
      ws[O_RGI+b*96+j]=sigm(a);
    } else if (j<192){
      int jj=j-96; float a=br2[jj]; const float* w=&Wr2[jj*EE];
      for(int e=0;e<EE;e++) a+=relL[e]*w[e];
      ws[O_RGT+b*96+jj]=sigm(a);
    } else {
      int k=j-192; float a=0; const float* w=&W1[k*1000+500];
      for(int e=0;e<EE;e++) a+=relL[e]*w[e];
      ws[O_RB+b*100+k]=a;
    }
  }
}

// ---------------- A^T[k,n] = (ent @ W1[:, :E]^T)^T ----------------
__global__ void k_A(const float* ent, const float* W1, float* ws){
  __shared__ __align__(16) float entL[8*EE];
  int n0 = blockIdx.x*8;
  for (int idx=threadIdx.x; idx<1000; idx+=256)
    *(float4*)&entL[idx*4] = *(const float4*)&ent[(size_t)n0*EE + idx*4];
  __syncthreads();
  for (int idx=threadIdx.x; idx<800; idx+=256){
    int k=idx>>3, rr=idx&7;
    const float4* el=(const float4*)&entL[rr*EE];
    const float4* wr=(const float4*)&W1[(size_t)k*1000];
    float s=0;
    for (int e4=0;e4<125;e4++){
      float4 a=el[e4], w=wr[e4];
      s += a.x*w.x + a.y*w.y + a.z*w.z + a.w*w.w;
    }
    ws[O_A + (size_t)k*NN + (n0+rr)] = s;
  }
}

// ---------------- pos_t vectors ----------------
__global__ void k_pos(const int* ps, const float* ent, const float* b1, const float* b3, float* ws){
  __shared__ float hL[KH];
  __shared__ float red[4];
  int b=blockIdx.x; int n=ps[b*3+2]; int tid=threadIdx.x;
  if (tid<KH) hL[tid] = leaky(ws[O_A+(size_t)tid*NN+n] + ws[O_RB+b*100+tid] + b1[tid]);
  __syncthreads();
  const float* w3t=&ws[O_W3T];
  float sq=0;
  for (int e=tid; e<EE; e+=256){
    float a=b3[e];
    for (int k=0;k<KH;k++) a += hL[k]*w3t[k*500+e];
    float gg=sigm(a); float ta=ent[(size_t)n*EE+e]*gg;
    ws[O_PT+b*500+e]=ta; sq+=ta*ta;
  }
  for (int off=1; off<64; off<<=1) sq += __shfl_xor(sq, off);
  if ((tid&63)==0) red[tid>>6]=sq;
  __syncthreads();
  if (tid==0) ws[O_PTN+b] = sqrtf(red[0]+red[1]+red[2]+red[3]);
}

// ---------------- embedding GEMM: block = 64 rows, 4 waves split F, LDS combine ----------------
// W rows read via wave-uniform address (scalar broadcast, L2-resident 80KB table).
__global__ __launch_bounds__(256) void k_emb2(const float* __restrict__ X,
                                              const float* __restrict__ Wp,
                                              const float* __restrict__ bias,
                                              float* __restrict__ emb,
                                              int R, int F, int rowsPerN, int rowOff,
                                              int xstride){
  __shared__ __align__(16) float part[4][64][52];   // 53 KB
  int tid = threadIdx.x;
  int lane = tid & 63;
  int w = __builtin_amdgcn_readfirstlane(tid >> 6);  // wave-uniform F-chunk id
  int row = blockIdx.x*64 + lane;
  int fq = (F + 3) >> 2;                 // 96 for F=383/384
  int f0 = w*fq;
  int f1 = min(F, f0+fq);
  float4 acc[13];
  #pragma unroll
  for (int c=0;c<13;c++) acc[c]=make_float4(0,0,0,0);
  if (row < R){
    const float* xr = X + (size_t)row*xstride;
    for (int f=f0; f<f1; ++f){
      float x = xr[f];
      const float4* wr = (const float4*)(Wp + (size_t)f*52);
      #pragma unroll
      for (int c=0;c<13;++c){
        float4 wv=wr[c];
        acc[c].x+=x*wv.x; acc[c].y+=x*wv.y; acc[c].z+=x*wv.z; acc[c].w+=x*wv.w;
      }
    }
  }
  #pragma unroll
  for (int c=0;c<13;c++) *(float4*)&part[w][lane][c*4] = acc[c];
  __syncthreads();
  // final: 64 rows x 13 float4 = 832 outputs; sum 4 partials + bias + leaky, coalesced store
  for (int g=tid; g<832; g+=256){
    int r = g/13, q = g-r*13;
    int row2 = blockIdx.x*64 + r;
    if (row2 < R){
      float4 s0 = *(const float4*)&part[0][r][q*4];
      float4 s1 = *(const float4*)&part[1][r][q*4];
      float4 s2 = *(const float4*)&part[2][r][q*4];
      float4 s3 = *(const float4*)&part[3][r][q*4];
      float4 v;
      v.x = leaky(s0.x+s1.x+s2.x+s3.x + bias[q*4+0]);
      v.y = leaky(s0.y+s1.y+s2.y+s3.y + bias[q*4+1]);
      v.z = (q<12)? leaky(s0.z+s1.z+s2.z+s3.z + bias[q*4+2]) : 0.f;
      v.w = (q<12)? leaky(s0.w+s1.w+s2.w+s3.w + bias[q*4+3]) : 0.f;
      int n = row2 / rowsPerN, rr = row2 % rowsPerN;
      *(float4*)&emb[(size_t)n*1456 + (size_t)(rowOff+rr)*52 + q*4] = v;
    }
  }
}

// ---------------- fused per-n kernel (mode 0: all n; mode 1: pos rows per b) ----------------
__global__ __launch_bounds__(256) void k_main(const int* ps, float* ws, float* out, int mode){
  __shared__ __align__(16) float teie[1456];
  __shared__ __align__(16) float Pm[120*52];
  __shared__ __align__(16) float Um[120*32];
  __shared__ __align__(16) float Gi[576];
  __shared__ __align__(16) float crs[96];
  __shared__ __align__(16) float aimg[96], atxt[96];
  __shared__ __align__(16) float part1[96], part2[96];
  __shared__ __align__(16) float aU[120];
  __shared__ float Gts[16], mimg[24], mtxt[4];
  __shared__ float muA1[4], muA2[24];
  __shared__ float accD1[32], accN1[32], accD2[32], accN2[32];

  int tid = threadIdx.x;
  int bstar = blockIdx.x;
  int n = mode ? ps[bstar*3+2] : blockIdx.x;

  // P0: stage emb row block, zero accumulators
  const float* embn = &ws[O_EMB + (size_t)n*1456];
  for (int j=tid; j<364; j+=256) *(float4*)&teie[j*4] = *(const float4*)&embn[j*4];
  if (tid<32){ accD1[tid]=0.f; accN1[tid]=0.f; accD2[tid]=0.f; accN2[tid]=0.f; }
  __syncthreads();

  // P1: Gram matrices, cross, means (vectorized; pad cols 50,51 are zero)
  for (int it=tid; it<716; it+=256){
    if (it<576){
      int i=it/24, j=it%24;
      const float4* a=(const float4*)&teie[(4+i)*52];
      const float4* b=(const float4*)&teie[(4+j)*52];
      float s=0;
      #pragma unroll
      for(int d=0;d<13;d++){ float4 x=a[d], y=b[d]; s+=x.x*y.x+x.y*y.y+x.z*y.z+x.w*y.w; }
      Gi[it]=s;
    } else if (it<672){
      int c=it-576; int i=c>>2, t=c&3;
      const float4* a=(const float4*)&teie[(4+i)*52];
      const float4* b=(const float4*)&teie[t*52];
      float s=0;
      #pragma unroll
      for(int d=0;d<13;d++){ float4 x=a[d], y=b[d]; s+=x.x*y.x+x.y*y.y+x.z*y.z+x.w*y.w; }
      crs[c]=s;
    } else if (it<688){
      int c=it-672; int t=c>>2, u=c&3;
      const float4* a=(const float4*)&teie[t*52];
      const float4* b=(const float4*)&teie[u*52];
      float s=0;
      #pragma unroll
      for(int d=0;d<13;d++){ float4 x=a[d], y=b[d]; s+=x.x*y.x+x.y*y.y+x.z*y.z+x.w*y.w; }
      Gts[c]=s;
    } else if (it<712){
      int i=it-688;
      const float4* a=(const float4*)&teie[(4+i)*52];
      float s=0;
      #pragma unroll
      for(int d=0;d<13;d++){ float4 x=a[d]; s+=x.x+x.y+x.z+x.w; }
      mimg[i]=s*0.02f;
    } else {
      int t=it-712;
      const float4* a=(const float4*)&teie[t*52];
      float s=0;
      #pragma unroll
      for(int d=0;d<13;d++){ float4 x=a[d]; s+=x.x+x.y+x.z+x.w; }
      mtxt[t]=s*0.02f;
    }
  }
  __syncthreads();

  // P2: attention softmaxes + means
  if (tid<4){
    int t=tid;
    float mx=-1e30f; for(int i=0;i<24;i++) mx=fmaxf(mx,crs[i*4+t]);
    float ex[24]; float s=0;
    for(int i=0;i<24;i++){ ex[i]=__expf(crs[i*4+t]-mx); s+=ex[i]; }
    float inv=1.f/s; float mu=0;
    for(int i=0;i<24;i++){ float a=ex[i]*inv; aimg[i*4+t]=a; mu+=a*mimg[i]; }
    muA1[t]=mu;
  } else if (tid>=64 && tid<88){
    int i=tid-64;
    float mx=-1e30f; for(int t=0;t<4;t++) mx=fmaxf(mx,crs[i*4+t]);
    float ex[4]; float s=0;
    for(int t=0;t<4;t++){ ex[t]=__expf(crs[i*4+t]-mx); s+=ex[t]; }
    float inv=1.f/s; float mu=0;
    for(int t=0;t<4;t++){ float a=ex[t]*inv; atxt[i*4+t]=a; mu+=a*mtxt[t]; }
    muA2[i]=mu;
  }
  __syncthreads();

  // P3: img Pm build (retiled: lane=(t,q,ig), 6 i-rows; w streamed from L2)
  if (tid<208){
    int ig=tid&3, r=tid>>2, q=r%13, t=r/13;
    const float* wb = &ws[O_WIP + (size_t)(t*13+q)*200];
    const float* eb = &teie[(4+ig*6)*52];
    float4 acc[6];
    #pragma unroll
    for (int l=0;l<6;l++) acc[l]=make_float4(0,0,0,0);
    for (int dc=0; dc<12; ++dc){
      float e[6][4];
      #pragma unroll
      for (int l=0;l<6;l++){
        float4 v=*(const float4*)&eb[l*52+dc*4];
        e[l][0]=v.x; e[l][1]=v.y; e[l][2]=v.z; e[l][3]=v.w;
      }
      #pragma unroll
      for (int dd=0; dd<4; ++dd){
        float4 w=*(const float4*)&wb[(dc*4+dd)*4];
        #pragma unroll
        for (int l=0;l<6;l++){
          acc[l].x+=e[l][dd]*w.x; acc[l].y+=e[l][dd]*w.y;
          acc[l].z+=e[l][dd]*w.z; acc[l].w+=e[l][dd]*w.w;
        }
      }
    }
    #pragma unroll
    for (int d=48; d<50; ++d){
      float4 w=*(const float4*)&wb[d*4];
      #pragma unroll
      for (int l=0;l<6;l++){
        float ee=eb[l*52+d];
        acc[l].x+=ee*w.x; acc[l].y+=ee*w.y; acc[l].z+=ee*w.z; acc[l].w+=ee*w.w;
      }
    }
    #pragma unroll
    for (int l=0;l<6;l++) *(float4*)&Pm[(t*24+ig*6+l)*52 + q*4]=acc[l];
  } else {
    // lanes 208..255: part1 (96), part2 (96), Sip copy (52 float4)
    for (int c=tid-208; c<244; c+=48){
      if (c<96){
        int i=c>>2, t=c&3;
        float s=0; for(int j=0;j<24;j++) s+=Gi[i*24+j]*aimg[j*4+t];
        part1[c]=aimg[c]*s;
      } else if (c<192){
        int cc=c-96; int t=cc&3;
        float s=0; for(int u=0;u<4;u++) s+=Gts[t*4+u]*atxt[(cc&~3)+u];
        part2[cc]=atxt[cc]*s;
      } else {
        int j=c-192;
        *(float4*)&Pm[96*52+j*4] = *(const float4*)&ws[O_SIP+j*4];
      }
    }
  }
  __syncthreads();

  // P4: img LN stats -> Um ; att aU
  if (tid<128){
    int b=tid&31, t=tid>>5;
    float w1r[24];
    #pragma unroll
    for(int i=0;i<24;i++) w1r[i]=ws[O_RGI+b*96+i*4+t]*crs[i*4+t];
    float mu=0;
    #pragma unroll
    for(int i=0;i<24;i++) mu+=w1r[i]*mimg[i];
    float q=0;
    #pragma unroll
    for(int i=0;i<24;i++){
      const float4* gr=(const float4*)&Gi[i*24];
      float s=0;
      #pragma unroll
      for(int j4=0;j4<6;j4++){
        float4 g=gr[j4];
        s+=g.x*w1r[j4*4]+g.y*w1r[j4*4+1]+g.z*w1r[j4*4+2]+g.w*w1r[j4*4+3];
      }
      q+=w1r[i]*s;
    }
    float inv=rsqrtf(q*0.02f-mu*mu+1e-5f);
    #pragma unroll
    for(int i=0;i<24;i++) Um[(t*24+i)*32+b]=inv*w1r[i];
    Um[(96+t)*32+b]=-inv*mu;
  } else if (tid<228){
    int z=tid-128;
    int t=(z<96)? (z/24) : (z-96);
    float q=0; for(int i=0;i<24;i++) q+=part1[i*4+t];
    float inv=rsqrtf(q*0.02f-muA1[t]*muA1[t]+1e-5f);
    aU[z]=(z<96)? inv*aimg[(z%24)*4+t] : -inv*muA1[t];
  }
  __syncthreads();

  // P5: img GEMM (4b x 4o per lane) + aU fold + CBI + fused cos-sim partials
  if (tid<104){
    int bg=tid/13, q=tid-bg*13;
    float4 a0=make_float4(0,0,0,0), a1=make_float4(0,0,0,0);
    float4 a2=make_float4(0,0,0,0), a3=make_float4(0,0,0,0);
    for (int z=0; z<100; ++z){
      float az=aU[z];
      float4 u=*(const float4*)&Um[z*32+bg*4];
      float4 p=*(const float4*)&Pm[z*52+q*4];
      float u0=u.x+az, u1=u.y+az, u2=u.z+az, u3=u.w+az;
      a0.x+=u0*p.x; a0.y+=u0*p.y; a0.z+=u0*p.z; a0.w+=u0*p.w;
      a1.x+=u1*p.x; a1.y+=u1*p.y; a1.z+=u1*p.z; a1.w+=u1*p.w;
      a2.x+=u2*p.x; a2.y+=u2*p.y; a2.z+=u2*p.z; a2.w+=u2*p.w;
      a3.x+=u3*p.x; a3.y+=u3*p.y; a3.z+=u3*p.z; a3.w+=u3*p.w;
    }
    float4 cb=*(const float4*)&ws[O_CBI+q*4];
    a0.x+=cb.x; a0.y+=cb.y; a0.z+=cb.z; a0.w+=cb.w;
    a1.x+=cb.x; a1.y+=cb.y; a1.z+=cb.z; a1.w+=cb.w;
    a2.x+=cb.x; a2.y+=cb.y; a2.z+=cb.z; a2.w+=cb.w;
    a3.x+=cb.x; a3.y+=cb.y; a3.z+=cb.z; a3.w+=cb.w;
    float n0=a0.x*a0.x+a0.y*a0.y+a0.z*a0.z+a0.w*a0.w;
    float n1=a1.x*a1.x+a1.y*a1.y+a1.z*a1.z+a1.w*a1.w;
    float n2=a2.x*a2.x+a2.y*a2.y+a2.z*a2.z+a2.w*a2.w;
    float n3=a3.x*a3.x+a3.y*a3.y+a3.z*a3.z+a3.w*a3.w;
    int b0=bg*4;
    if (!mode){
      const float* PV=&ws[O_PIM];
      float4 p0=*(const float4*)&PV[(b0+0)*52+q*4];
      float4 p1=*(const float4*)&PV[(b0+1)*52+q*4];
      float4 p2=*(const float4*)&PV[(b0+2)*52+q*4];
      float4 p3=*(const float4*)&PV[(b0+3)*52+q*4];
      atomicAdd(&accD1[b0+0], a0.x*p0.x+a0.y*p0.y+a0.z*p0.z+a0.w*p0.w);
      atomicAdd(&accD1[b0+1], a1.x*p1.x+a1.y*p1.y+a1.z*p1.z+a1.w*p1.w);
      atomicAdd(&accD1[b0+2], a2.x*p2.x+a2.y*p2.y+a2.z*p2.z+a2.w*p2.w);
      atomicAdd(&accD1[b0+3], a3.x*p3.x+a3.y*p3.y+a3.z*p3.z+a3.w*p3.w);
      atomicAdd(&accN1[b0+0],n0); atomicAdd(&accN1[b0+1],n1);
      atomicAdd(&accN1[b0+2],n2); atomicAdd(&accN1[b0+3],n3);
    } else {
      atomicAdd(&accN1[b0+0],n0); atomicAdd(&accN1[b0+1],n1);
      atomicAdd(&accN1[b0+2],n2); atomicAdd(&accN1[b0+3],n3);
      if ((bstar>>2)==bg){
        int bl=bstar&3;
        float4 sel = (bl==0)? a0 : (bl==1)? a1 : (bl==2)? a2 : a3;
        *(float4*)&ws[O_PIM+(size_t)bstar*52+q*4]=sel;
      }
    }
  }
  __syncthreads();

  // P6: write img sims / norms; build text Pm (retiled) + Stp copy
  if (!mode){
    if (tid<32)
      out[(size_t)BN + (size_t)tid*NN + n] = accD1[tid]/(sqrtf(accN1[tid])*ws[O_PIMN+tid]+1e-10f);
  } else {
    if (tid==0) ws[O_PIMN+bstar]=sqrtf(accN1[bstar]);
  }
  if (tid<156){
    int q=tid%13, i2=tid/13;   // i2 0..11 -> i = 2*i2, 2*i2+1
    const float* wbA = &ws[O_WTP + (size_t)((i2*2+0)*13+q)*200];
    const float* wbB = &ws[O_WTP + (size_t)((i2*2+1)*13+q)*200];
    float4 accA[4], accB[4];
    #pragma unroll
    for (int t=0;t<4;t++){ accA[t]=make_float4(0,0,0,0); accB[t]=make_float4(0,0,0,0); }
    for (int dc=0; dc<12; ++dc){
      float e[4][4];
      #pragma unroll
      for (int t=0;t<4;t++){
        float4 v=*(const float4*)&teie[t*52+dc*4];
        e[t][0]=v.x; e[t][1]=v.y; e[t][2]=v.z; e[t][3]=v.w;
      }
      #pragma unroll
      for (int dd=0; dd<4; ++dd){
        float4 wA=*(const float4*)&wbA[(dc*4+dd)*4];
        float4 wB=*(const float4*)&wbB[(dc*4+dd)*4];
        #pragma unroll
        for (int t=0;t<4;t++){
          accA[t].x+=e[t][dd]*wA.x; accA[t].y+=e[t][dd]*wA.y;
          accA[t].z+=e[t][dd]*wA.z; accA[t].w+=e[t][dd]*wA.w;
          accB[t].x+=e[t][dd]*wB.x; accB[t].y+=e[t][dd]*wB.y;
          accB[t].z+=e[t][dd]*wB.z; accB[t].w+=e[t][dd]*wB.w;
        }
      }
    }
    #pragma unroll
    for (int d=48; d<50; ++d){
      float4 wA=*(const float4*)&wbA[d*4];
      float4 wB=*(const float4*)&wbB[d*4];
      #pragma unroll
      for (int t=0;t<4;t++){
        float ee=teie[t*52+d];
        accA[t].x+=ee*wA.x; accA[t].y+=ee*wA.y; accA[t].z+=ee*wA.z; accA[t].w+=ee*wA.w;
        accB[t].x+=ee*wB.x; accB[t].y+=ee*wB.y; accB[t].z+=ee*wB.z; accB[t].w+=ee*wB.w;
      }
    }
    #pragma unroll
    for (int t=0;t<4;t++){
      *(float4*)&Pm[(t*24+i2*2+0)*52 + q*4]=accA[t];
      *(float4*)&Pm[(t*24+i2*2+1)*52 + q*4]=accB[t];
    }
  } else {
    for (int j=tid-156; j<312; j+=100)
      *(float4*)&Pm[96*52+j*4] = *(const float4*)&ws[O_STP+j*4];
  }
  __syncthreads();

  // P7: text LN stats -> Um ; att aU2
  for (int it=tid; it<888; it+=256){
    if (it<768){
      int b=it&31, i=it>>5;
      float w2r[4];
      #pragma unroll
      for(int t=0;t<4;t++) w2r[t]=ws[O_RGT+b*96+i*4+t]*crs[i*4+t];
      float mu=0;
      #pragma unroll
      for(int t=0;t<4;t++) mu+=w2r[t]*mtxt[t];
      float q=0;
      #pragma unroll
      for(int t=0;t<4;t++){
        float s=0;
        #pragma unroll
        for(int u=0;u<4;u++) s+=Gts[t*4+u]*w2r[u];
        q+=w2r[t]*s;
      }
      float inv=rsqrtf(q*0.02f-mu*mu+1e-5f);
      #pragma unroll
      for(int t=0;t<4;t++) Um[(t*24+i)*32+b]=inv*w2r[t];
      Um[(96+i)*32+b]=-inv*mu;
    } else {
      int z=it-768;
      int i=(z<96)? (z%24) : (z-96);
      float q=0; for(int t=0;t<4;t++) q+=part2[i*4+t];
      float inv=rsqrtf(q*0.02f-muA2[i]*muA2[i]+1e-5f);
      aU[z]=(z<96)? inv*atxt[(z%24)*4+(z/24)] : -inv*muA2[i];
    }
  }
  __syncthreads();

  // P7b: QattC fold is inside P8 via aU
  // P8: text GEMM (4b x 4o per lane) + aU fold + CBT + fused cos-sim partials
  if (tid<104){
    int bg=tid/13, q=tid-bg*13;
    float4 a0=make_float4(0,0,0,0), a1=make_float4(0,0,0,0);
    float4 a2=make_float4(0,0,0,0), a3=make_float4(0,0,0,0);
    for (int z=0; z<120; ++z){
      float az=aU[z];
      float4 u=*(const float4*)&Um[z*32+bg*4];
      float4 p=*(const float4*)&Pm[z*52+q*4];
      float u0=u.x+az, u1=u.y+az, u2=u.z+az, u3=u.w+az;
      a0.x+=u0*p.x; a0.y+=u0*p.y; a0.z+=u0*p.z; a0.w+=u0*p.w;
      a1.x+=u1*p.x; a1.y+=u1*p.y; a1.z+=u1*p.z; a1.w+=u1*p.w;
      a2.x+=u2*p.x; a2.y+=u2*p.y; a2.z+=u2*p.z; a2.w+=u2*p.w;
      a3.x+=u3*p.x; a3.y+=u3*p.y; a3.z+=u3*p.z; a3.w+=u3*p.w;
    }
    float4 cb=*(const float4*)&ws[O_CBT+q*4];
    a0.x+=cb.x; a0.y+=cb.y; a0.z+=cb.z; a0.w+=cb.w;
    a1.x+=cb.x; a1.y+=cb.y; a1.z+=cb.z; a1.w+=cb.w;
    a2.x+=cb.x; a2.y+=cb.y; a2.z+=cb.z; a2.w+=cb.w;
    a3.x+=cb.x; a3.y+=cb.y; a3.z+=cb.z; a3.w+=cb.w;
    float n0=a0.x*a0.x+a0.y*a0.y+a0.z*a0.z+a0.w*a0.w;
    float n1=a1.x*a1.x+a1.y*a1.y+a1.z*a1.z+a1.w*a1.w;
    float n2=a2.x*a2.x+a2.y*a2.y+a2.z*a2.z+a2.w*a2.w;
    float n3=a3.x*a3.x+a3.y*a3.y+a3.z*a3.z+a3.w*a3.w;
    int b0=bg*4;
    if (!mode){
      const float* PV=&ws[O_PTX];
      float4 p0=*(const float4*)&PV[(b0+0)*52+q*4];
      float4 p1=*(const float4*)&PV[(b0+1)*52+q*4];
      float4 p2=*(const float4*)&PV[(b0+2)*52+q*4];
      float4 p3=*(const float4*)&PV[(b0+3)*52+q*4];
      atomicAdd(&accD2[b0+0], a0.x*p0.x+a0.y*p0.y+a0.z*p0.z+a0.w*p0.w);
      atomicAdd(&accD2[b0+1], a1.x*p1.x+a1.y*p1.y+a1.z*p1.z+a1.w*p1.w);
      atomicAdd(&accD2[b0+2], a2.x*p2.x+a2.y*p2.y+a2.z*p2.z+a2.w*p2.w);
      atomicAdd(&accD2[b0+3], a3.x*p3.x+a3.y*p3.y+a3.z*p3.z+a3.w*p3.w);
      atomicAdd(&accN2[b0+0],n0); atomicAdd(&accN2[b0+1],n1);
      atomicAdd(&accN2[b0+2],n2); atomicAdd(&accN2[b0+3],n3);
    } else {
      atomicAdd(&accN2[b0+0],n0); atomicAdd(&accN2[b0+1],n1);
      atomicAdd(&accN2[b0+2],n2); atomicAdd(&accN2[b0+3],n3);
      if ((bstar>>2)==bg){
        int bl=bstar&3;
        float4 sel = (bl==0)? a0 : (bl==1)? a1 : (bl==2)? a2 : a3;
        *(float4*)&ws[O_PTX+(size_t)bstar*52+q*4]=sel;
      }
    }
  }
  __syncthreads();

  // P9: write text sims / norms
  if (!mode){
    if (tid<32)
      out[2*(size_t)BN + (size_t)tid*NN + n] = accD2[tid]/(sqrtf(accN2[tid])*ws[O_PTXN+tid]+1e-10f);
  } else {
    if (tid==0) ws[O_PTXN+bstar]=sqrtf(accN2[bstar]);
  }
}

// ---------------- gate GEMM + t-path cos-sim, blocked: (b, 64-n tile) per block ----------------
__global__ __launch_bounds__(256) void k_gate(const float* ent, const float* b1, const float* b3,
                                              float* ws, float* out){
  __shared__ __align__(16) float hL[50*68];    // [k][64n] pad->68  13.6 KB
  __shared__ __align__(16) float wc[50*128];   // [k][128e]         25.6 KB
  __shared__ __align__(16) float PTb[512];     // pos_t[b] padded    2 KB
  __shared__ __align__(16) float b3L[512];     // b3 padded          2 KB
  __shared__ float rbL[KH];                    // RB[b,:]+b1

  int tid = threadIdx.x;
  int b   = blockIdx.x & 31;
  int n0  = (blockIdx.x >> 5) * 64;

  for (int j=tid; j<512; j+=256){
    PTb[j] = (j<EE)? ws[O_PT + b*EE + j] : 0.f;
    b3L[j] = (j<EE)? b3[j] : 0.f;
  }
  if (tid < KH) rbL[tid] = ws[O_RB + b*KH + tid] + b1[tid];

  int ej = tid & 31;   // e-group lane: 4 e each
  int ni = tid >> 5;   // n-group: 8 n each

  float pn[8], ps[8];
  #pragma unroll
  for (int r=0;r<8;r++){ pn[r]=0.f; ps[r]=0.f; }

  for (int ec=0; ec<4; ++ec){
    int e0 = ec*128;
    float4 acc[8];
    #pragma unroll
    for (int r=0;r<8;r++) acc[r]=make_float4(0,0,0,0);

    for (int kh=0; kh<2; ++kh){
      __syncthreads();
      for (int idx=tid; idx<1600; idx+=256){
        int k = idx>>5, j4 = idx&31;
        int e = e0 + j4*4;
        float4 v = make_float4(0,0,0,0);
        if (e+3 < EE) v = *(const float4*)&ws[O_W3T + (size_t)(kh*50+k)*EE + e];
        *(float4*)&wc[k*128 + j4*4] = v;
      }
      for (int idx=tid; idx<3200; idx+=256){
        int k = idx>>6, nn = idx&63;
        int n = n0 + nn;
        float v = 0.f;
        if (n < NN) v = leaky(ws[O_A + (size_t)(kh*50+k)*NN + n] + rbL[kh*50+k]);
        hL[k*68 + nn] = v;
      }
      __syncthreads();

      const float4* wp = (const float4*)&wc[ej*4];   // stride 32 float4 per k
      const float4* hp = (const float4*)&hL[ni*8];   // stride 17 float4 per k
      #pragma unroll 2
      for (int k=0;k<50;k++){
        float4 w  = wp[k*32];
        float4 h0 = hp[k*17];
        float4 h1 = hp[k*17 + 1];
        acc[0].x+=h0.x*w.x; acc[0].y+=h0.x*w.y; acc[0].z+=h0.x*w.z; acc[0].w+=h0.x*w.w;
        acc[1].x+=h0.y*w.x; acc[1].y+=h0.y*w.y; acc[1].z+=h0.y*w.z; acc[1].w+=h0.y*w.w;
        acc[2].x+=h0.z*w.x; acc[2].y+=h0.z*w.y; acc[2].z+=h0.z*w.z; acc[2].w+=h0.z*w.w;
        acc[3].x+=h0.w*w.x; acc[3].y+=h0.w*w.y; acc[3].z+=h0.w*w.z; acc[3].w+=h0.w*w.w;
        acc[4].x+=h1.x*w.x; acc[4].y+=h1.x*w.y; acc[4].z+=h1.x*w.z; acc[4].w+=h1.x*w.w;
        acc[5].x+=h1.y*w.x; acc[5].y+=h1.y*w.y; acc[5].z+=h1.y*w.z; acc[5].w+=h1.y*w.w;
        acc[6].x+=h1.z*w.x; acc[6].y+=h1.z*w.y; acc[6].z+=h1.z*w.z; acc[6].w+=h1.z*w.w;
        acc[7].x+=h1.w*w.x; acc[7].y+=h1.w*w.y; acc[7].z+=h1.w*w.z; acc[7].w+=h1.w*w.w;
      }
    }

    {
      int ebase = e0 + ej*4;
      bool ev = (ebase + 3) < EE;
      float4 bb = *(const float4*)&b3L[ebase];
      float4 pt = *(const float4*)&PTb[ebase];
      #pragma unroll
      for (int r=0;r<8;r++){
        int n = n0 + ni*8 + r;
        float4 en = make_float4(0,0,0,0);
        if (ev && n < NN) en = *(const float4*)&ent[(size_t)n*EE + ebase];
        float t0 = en.x * sigm(acc[r].x + bb.x);
        float t1 = en.y * sigm(acc[r].y + bb.y);
        float t2 = en.z * sigm(acc[r].z + bb.z);
        float t3 = en.w * sigm(acc[r].w + bb.w);
        pn[r] += t0*pt.x + t1*pt.y + t2*pt.z + t3*pt.w;
        ps[r] += t0*t0 + t1*t1 + t2*t2 + t3*t3;
      }
    }
  }

  for (int off=1; off<32; off<<=1){
    #pragma unroll
    for (int r=0;r<8;r++){ pn[r]+=__shfl_xor(pn[r],off); ps[r]+=__shfl_xor(ps[r],off); }
  }
  if (ej==0){
    float ptn = ws[O_PTN+b];
    #pragma unroll
    for (int r=0;r<8;r++){
      int n = n0 + ni*8 + r;
      if (n < NN)
        out[3*(size_t)BN + (size_t)b*NN + n] = pn[r]/(sqrtf(ps[r])*ptn + 1e-10f);
    }
  }
}

// ---------------- softmax pass 1 ----------------
__global__ void k_smax1(const float* out, float* ws){
  __shared__ float red[4];
  __shared__ float Msh;
  int a=blockIdx.x>>5, b=blockIdx.x&31, tid=threadIdx.x;
  const float* arr=&out[(size_t)(1+a)*BN + (size_t)b*NN];
  float mx=-1e30f;
  for (int i=tid;i<NN;i+=256) mx=fmaxf(mx,arr[i]);
  for (int off=1;off<64;off<<=1) mx=fmaxf(mx,__shfl_xor(mx,off));
  if ((tid&63)==0) red[tid>>6]=mx;
  __syncthreads();
  if (tid==0) Msh=fmaxf(fmaxf(red[0],red[1]),fmaxf(red[2],red[3]));
  __syncthreads();
  float M2=2.f*Msh;
  float s=0;
  for (int i=tid;i<NN;i+=256) s+=__expf(2.f*arr[i]-M2);
  for (int off=1;off<64;off<<=1) s+=__shfl_xor(s,off);
  if ((tid&63)==0) red[tid>>6]=s;
  __syncthreads();
  if (tid==0){ ws[O_MR+a*32+b]=M2; ws[O_SR+a*32+b]=red[0]+red[1]+red[2]+red[3]; }
}

// ---------------- softmax pass 2 ----------------
__global__ void k_smax2(float* out, const float* ws){
  int t=blockIdx.x*256+threadIdx.x;
  if (t>=BN) return;
  int b=t/NN;
  float r=0;
  for (int a=0;a<3;a++)
    r += __expf(2.f*out[(size_t)(1+a)*BN+t]-ws[O_MR+a*32+b])/ws[O_SR+a*32+b];
  out[t]=r;
}

extern "C" void kernel_launch(void* const* d_in, const int* in_sizes, int n_in,
                              void* d_out, int out_size, void* d_ws, size_t ws_size,
                              hipStream_t stream){
  (void)in_sizes; (void)n_in; (void)out_size; (void)ws_size;
  const int*   ps  =(const int*)  d_in[0];
  const float* etg =(const float*)d_in[1];
  const float* eig =(const float*)d_in[2];
  const float* ent =(const float*)d_in[3];
  const float* rele=(const float*)d_in[4];
  const float* Wt  =(const float*)d_in[5];
  const float* btx =(const float*)d_in[6];
  const float* Wi  =(const float*)d_in[7];
  const float* bim =(const float*)d_in[8];
  const float* Wtp =(const float*)d_in[9];
  const float* btp =(const float*)d_in[10];
  const float* Wip =(const float*)d_in[11];
  const float* bip =(const float*)d_in[12];
  const float* Wr1 =(const float*)d_in[13];
  const float* br1 =(const float*)d_in[14];
  const float* Wr2 =(const float*)d_in[15];
  const float* br2 =(const float*)d_in[16];
  const float* W1  =(const float*)d_in[17];
  const float* b1  =(const float*)d_in[18];
  const float* W3  =(const float*)d_in[19];
  const float* b3  =(const float*)d_in[20];
  const float* lng =(const float*)d_in[21];
  const float* lnb =(const float*)d_in[22];
  float* ws =(float*)d_ws;
  float* out=(float*)d_out;

  k_prep <<<642,256,0,stream>>>(Wt,Wi,Wip,Wtp,W1,W3,lng,lnb,bip,btp,ws);
  k_rel  <<<32, 256,0,stream>>>(ps,rele,Wr1,br1,Wr2,br2,W1,ws);
  k_A    <<<625,256,0,stream>>>(ent,W1,ws);
  k_pos  <<<32, 256,0,stream>>>(ps,ent,b1,b3,ws);
  k_emb2 <<<313, 256,0,stream>>>(etg,&ws[O_WTT],btx,&ws[O_EMB],20000,FT,4,0,FT);
  k_emb2 <<<1875,256,0,stream>>>(eig,&ws[O_WIT],bim,&ws[O_EMB],120000,FI,24,4,FI);
  k_main <<<32,  256,0,stream>>>(ps,ws,out,1);
  k_main <<<5000,256,0,stream>>>(ps,ws,out,0);
  k_gate <<<32*79,256,0,stream>>>(ent,b1,b3,ws,out);
  k_smax1<<<96, 256,0,stream>>>(out,ws);
  k_smax2<<<625,256,0,stream>>>(out,ws);
}